// Round 1
// baseline (22441.113 us; speedup 1.0000x reference)
//
#include <hip/hip_runtime.h>
#include <hip/hip_cooperative_groups.h>

namespace cg = cooperative_groups;

#define N 8192
#define TPB 256
#define NBLK 1024
#define N_ITERS 50
#define ROWS_PER_BLK 8      // N / NBLK
#define COL_TILES 32        // N / TPB
#define CHUNKS 32           // NBLK / COL_TILES
#define ROWS_PER_CHUNK 256  // N / CHUNKS
#define NV4 (N * N / 4)

__device__ __forceinline__ float wave_sum(float v) {
#pragma unroll
  for (int o = 32; o > 0; o >>= 1) v += __shfl_down(v, o, 64);
  return v;
}
__device__ __forceinline__ float wave_max(float v) {
#pragma unroll
  for (int o = 32; o > 0; o >>= 1) v = fmaxf(v, __shfl_down(v, o, 64));
  return v;
}

// All 256 threads receive the reduced value. sm4 holds 4 floats (4 waves).
__device__ __forceinline__ float block_sum(float v, float* sm4) {
  v = wave_sum(v);
  const int wave = threadIdx.x >> 6, lane = threadIdx.x & 63;
  __syncthreads();
  if (lane == 0) sm4[wave] = v;
  __syncthreads();
  return sm4[0] + sm4[1] + sm4[2] + sm4[3];
}
__device__ __forceinline__ float block_max(float v, float* sm4) {
  v = wave_max(v);
  const int wave = threadIdx.x >> 6, lane = threadIdx.x & 63;
  __syncthreads();
  if (lane == 0) sm4[wave] = v;
  __syncthreads();
  return fmaxf(fmaxf(sm4[0], sm4[1]), fmaxf(sm4[2], sm4[3]));
}

// Scaled potentials: F = f/eps, G = g/eps (eps=0.1 => 1/eps=10, and
// f/eps = log(a) - lse since eps*(1/eps)=1). logP = 10*M + F_i + G_j.
__global__ __launch_bounds__(TPB, 4) void sinkhorn_kernel(
    const float* __restrict__ M, const float* __restrict__ T,
    const float* __restrict__ av, const float* __restrict__ bv,
    float* __restrict__ out, float* __restrict__ F, float* __restrict__ G,
    float* __restrict__ ps, float* __restrict__ pshift,
    float* __restrict__ gmaxp, float* __restrict__ acc) {
  cg::grid_group grid = cg::this_grid();
  const int tid = threadIdx.x;
  const int bid = blockIdx.x;
  __shared__ float sm4[4];
  __shared__ float sf[ROWS_PER_CHUNK];

  // ---- init: G = 0 (g0 = 0), per-combine-block G maxima = 0, acc = 0 ----
  if (bid < COL_TILES) G[bid * TPB + tid] = 0.0f;
  if (bid == 0) {
    if (tid < CHUNKS) gmaxp[tid] = 0.0f;
    if (tid == 0) acc[0] = 0.0f;
  }
  grid.sync();

  for (int it = 0; it < N_ITERS; ++it) {
    // ---- row phase: F[i] = log a[i] - lse_j(10*M[i,j] + G[j]) ----
    // shift = 10 + Gmax guarantees exp args <= 0; s >= e^-10 so log(s) is safe.
    float gmax = gmaxp[0];
#pragma unroll
    for (int c = 1; c < CHUNKS; ++c) gmax = fmaxf(gmax, gmaxp[c]);
    const float rshift = 10.0f + gmax;
    for (int r = 0; r < ROWS_PER_BLK; ++r) {
      const int row = bid * ROWS_PER_BLK + r;
      const float4* M4 = (const float4*)(M + (size_t)row * N);
      const float4* G4 = (const float4*)G;
      float s = 0.0f;
#pragma unroll 2
      for (int v = tid; v < N / 4; v += TPB) {
        const float4 m4 = M4[v];
        const float4 g4 = G4[v];
        s += __expf(fmaf(m4.x, 10.0f, g4.x - rshift));
        s += __expf(fmaf(m4.y, 10.0f, g4.y - rshift));
        s += __expf(fmaf(m4.z, 10.0f, g4.z - rshift));
        s += __expf(fmaf(m4.w, 10.0f, g4.w - rshift));
      }
      s = block_sum(s, sm4);
      if (tid == 0) F[row] = __logf(av[row]) - (rshift + __logf(s));
    }
    grid.sync();

    // ---- col phase: per-chunk partial sums for lse_i(10*M[i,j] + F[i]) ----
    {
      const int tile = bid & (COL_TILES - 1);
      const int chunk = bid >> 5;  // log2(COL_TILES)
      const int col = tile * TPB + tid;
      const int r0 = chunk * ROWS_PER_CHUNK;
      const float fv = F[r0 + tid];
      const float fmax_c = block_max(fv, sm4);
      const float cshift = 10.0f + fmax_c;
      sf[tid] = fv - cshift;
      __syncthreads();
      float s = 0.0f;
      const float* Mp = M + (size_t)r0 * N + col;
#pragma unroll 4
      for (int i = 0; i < ROWS_PER_CHUNK; ++i) {
        s += __expf(fmaf(Mp[(size_t)i * N], 10.0f, sf[i]));
      }
      ps[chunk * N + col] = s;
      if (tile == 0 && tid == 0) pshift[chunk] = cshift;
      __syncthreads();
    }
    grid.sync();

    // ---- combine phase: 32 blocks merge 32 (shift, sum) partials per col ----
    if (bid < COL_TILES) {
      const int j = bid * TPB + tid;
      float mm = -1e30f, ss = 0.0f;
#pragma unroll 4
      for (int c = 0; c < CHUNKS; ++c) {
        const float cm = pshift[c];
        const float cs = ps[c * N + j];
        const float nm = fmaxf(mm, cm);
        ss = ss * __expf(mm - nm) + cs * __expf(cm - nm);
        mm = nm;
      }
      const float gv = __logf(bv[j]) - (mm + __logf(ss));
      G[j] = gv;
      const float bm = block_max(gv, sm4);
      if (tid == 0) gmaxp[bid] = bm;
    }
    grid.sync();
  }

  // ---- cross-entropy: -(sum target * (10*M + F_i + G_j)) ----
  {
    float s = 0.0f;
    const float4* M4 = (const float4*)M;
    const float4* T4 = (const float4*)T;
    const float4* G4 = (const float4*)G;
    for (int v = bid * TPB + tid; v < NV4; v += NBLK * TPB) {
      const int row = v >> 11;           // (4v) / 8192
      const int gc = v & (N / 4 - 1);
      const float4 m4 = M4[v];
      const float4 t4 = T4[v];
      const float4 g4 = G4[gc];
      const float Fi = F[row];
      s += t4.x * (fmaf(m4.x, 10.0f, Fi) + g4.x);
      s += t4.y * (fmaf(m4.y, 10.0f, Fi) + g4.y);
      s += t4.z * (fmaf(m4.z, 10.0f, Fi) + g4.z);
      s += t4.w * (fmaf(m4.w, 10.0f, Fi) + g4.w);
    }
    s = block_sum(s, sm4);
    if (tid == 0) atomicAdd(acc, s);
  }
  grid.sync();
  if (bid == 0 && tid == 0) out[0] = -acc[0];
}

extern "C" void kernel_launch(void* const* d_in, const int* in_sizes, int n_in,
                              void* d_out, int out_size, void* d_ws, size_t ws_size,
                              hipStream_t stream) {
  const float* M = (const float*)d_in[0];
  const float* T = (const float*)d_in[1];
  const float* av = (const float*)d_in[2];
  const float* bv = (const float*)d_in[3];
  float* out = (float*)d_out;

  float* ws = (float*)d_ws;
  float* F = ws;                       // N floats
  float* G = ws + N;                   // N floats
  float* ps = ws + 2 * N;              // CHUNKS*N floats (1 MB)
  float* pshift = ps + CHUNKS * N;     // CHUNKS floats
  float* gmaxp = pshift + CHUNKS;      // COL_TILES floats
  float* acc = gmaxp + COL_TILES;      // 1 float

  void* args[] = {&M, &T, &av, &bv, &out, &F, &G, &ps, &pshift, &gmaxp, &acc};
  hipLaunchCooperativeKernel((const void*)sinkhorn_kernel, dim3(NBLK), dim3(TPB),
                             args, 0, stream);
}

// Round 2
// 20847.055 us; speedup vs baseline: 1.0765x; 1.0765x over previous
//
#include <hip/hip_runtime.h>
#include <hip/hip_cooperative_groups.h>

namespace cg = cooperative_groups;

#define N 8192
#define TPB 256
#define NBLK 1024
#define N_ITERS 50
#define ROWS_PER_BLK 8      // N / NBLK
#define COL_TILES 32        // N / TPB
#define CHUNKS 32           // NBLK / COL_TILES
#define ROWS_PER_CHUNK 256  // N / CHUNKS
#define NV4 (N * N / 4)

// ---- custom grid barrier: 32 groups x 32 blocks + root + generation flag ----
#define NG 32
#define GSZ 32
#define CSTRIDE 32  // uints (128 B) per counter to avoid line sharing
// bar layout (uints): [g*CSTRIDE] group counters, [NG*CSTRIDE] root,
//                     [NG*CSTRIDE + CSTRIDE] generation
#define BAR_UINTS (NG * CSTRIDE + 2 * CSTRIDE)

__device__ __forceinline__ void gbar(unsigned* bar, int bid, unsigned k) {
  __syncthreads();
  if (threadIdx.x == 0) {
    __threadfence();  // release prior writes (agent scope)
    const int g = bid & (NG - 1);  // bids g, g+32, ... share an XCD (32 % 8 == 0)
    unsigned prev = __hip_atomic_fetch_add(&bar[g * CSTRIDE], 1u,
                                           __ATOMIC_ACQ_REL, __HIP_MEMORY_SCOPE_AGENT);
    if (prev == k * GSZ - 1) {  // last arrival in this group this round
      unsigned rprev = __hip_atomic_fetch_add(&bar[NG * CSTRIDE], 1u,
                                              __ATOMIC_ACQ_REL, __HIP_MEMORY_SCOPE_AGENT);
      if (rprev == k * NG - 1) {  // last group leader: open the barrier
        __hip_atomic_store(&bar[NG * CSTRIDE + CSTRIDE], k,
                           __ATOMIC_RELEASE, __HIP_MEMORY_SCOPE_AGENT);
      }
    }
    while (__hip_atomic_load(&bar[NG * CSTRIDE + CSTRIDE],
                             __ATOMIC_ACQUIRE, __HIP_MEMORY_SCOPE_AGENT) < k) {
      __builtin_amdgcn_s_sleep(1);
    }
  }
  __syncthreads();
}

__device__ __forceinline__ float wave_sum(float v) {
#pragma unroll
  for (int o = 32; o > 0; o >>= 1) v += __shfl_down(v, o, 64);
  return v;
}
__device__ __forceinline__ float wave_max(float v) {
#pragma unroll
  for (int o = 32; o > 0; o >>= 1) v = fmaxf(v, __shfl_down(v, o, 64));
  return v;
}

__device__ __forceinline__ float block_sum(float v, float* sm4) {
  v = wave_sum(v);
  const int wave = threadIdx.x >> 6, lane = threadIdx.x & 63;
  __syncthreads();
  if (lane == 0) sm4[wave] = v;
  __syncthreads();
  return sm4[0] + sm4[1] + sm4[2] + sm4[3];
}
__device__ __forceinline__ float block_max(float v, float* sm4) {
  v = wave_max(v);
  const int wave = threadIdx.x >> 6, lane = threadIdx.x & 63;
  __syncthreads();
  if (lane == 0) sm4[wave] = v;
  __syncthreads();
  return fmaxf(fmaxf(sm4[0], sm4[1]), fmaxf(sm4[2], sm4[3]));
}

// Scaled potentials: F = f/eps, G = g/eps (eps=0.1 => 1/eps=10, and
// f/eps = log(a) - lse since eps*(1/eps)=1). logP = 10*M + F_i + G_j.
__global__ __launch_bounds__(TPB, 4) void sinkhorn_kernel(
    const float* __restrict__ M, const float* __restrict__ T,
    const float* __restrict__ av, const float* __restrict__ bv,
    float* __restrict__ out, float* __restrict__ F, float* __restrict__ G,
    float* __restrict__ ps, float* __restrict__ pshift,
    float* __restrict__ gmaxp, float* __restrict__ acc,
    unsigned* __restrict__ bar) {
  cg::grid_group grid = cg::this_grid();
  const int tid = threadIdx.x;
  const int bid = blockIdx.x;
  __shared__ float sm4[4];
  __shared__ float sf[ROWS_PER_CHUNK];

  // ---- init: G = 0 (g0 = 0), combine maxima = 0, acc = 0, barrier = 0 ----
  if (bid < COL_TILES) G[bid * TPB + tid] = 0.0f;
  if (bid == 0) {
    if (tid < CHUNKS) gmaxp[tid] = 0.0f;
    if (tid == 0) acc[0] = 0.0f;
    for (int i = tid; i < BAR_UINTS; i += TPB) bar[i] = 0u;
  }
  grid.sync();  // one (slow) cg sync to publish zeroed barrier state
  unsigned bk = 0;

  for (int it = 0; it < N_ITERS; ++it) {
    // ---- row phase: F[i] = log a[i] - lse_j(10*M[i,j] + G[j]) ----
    float gmax = gmaxp[0];
#pragma unroll
    for (int c = 1; c < CHUNKS; ++c) gmax = fmaxf(gmax, gmaxp[c]);
    const float rshift = 10.0f + gmax;
    for (int r = 0; r < ROWS_PER_BLK; ++r) {
      const int row = bid * ROWS_PER_BLK + r;
      const float4* M4 = (const float4*)(M + (size_t)row * N);
      const float4* G4 = (const float4*)G;
      float s = 0.0f;
#pragma unroll 2
      for (int v = tid; v < N / 4; v += TPB) {
        const float4 m4 = M4[v];
        const float4 g4 = G4[v];
        s += __expf(fmaf(m4.x, 10.0f, g4.x - rshift));
        s += __expf(fmaf(m4.y, 10.0f, g4.y - rshift));
        s += __expf(fmaf(m4.z, 10.0f, g4.z - rshift));
        s += __expf(fmaf(m4.w, 10.0f, g4.w - rshift));
      }
      s = block_sum(s, sm4);
      if (tid == 0) F[row] = __logf(av[row]) - (rshift + __logf(s));
    }
    gbar(bar, bid, ++bk);

    // ---- col phase: per-chunk partial sums for lse_i(10*M[i,j] + F[i]) ----
    {
      const int tile = bid & (COL_TILES - 1);
      const int chunk = bid >> 5;
      const int col = tile * TPB + tid;
      const int r0 = chunk * ROWS_PER_CHUNK;
      const float fv = F[r0 + tid];
      const float fmax_c = block_max(fv, sm4);
      const float cshift = 10.0f + fmax_c;
      sf[tid] = fv - cshift;
      __syncthreads();
      float s = 0.0f;
      const float* Mp = M + (size_t)r0 * N + col;
#pragma unroll 4
      for (int i = 0; i < ROWS_PER_CHUNK; ++i) {
        s += __expf(fmaf(Mp[(size_t)i * N], 10.0f, sf[i]));
      }
      ps[chunk * N + col] = s;
      if (tile == 0 && tid == 0) pshift[chunk] = cshift;
      __syncthreads();
    }
    gbar(bar, bid, ++bk);

    // ---- combine phase: 32 blocks merge 32 (shift, sum) partials per col ----
    if (bid < COL_TILES) {
      const int j = bid * TPB + tid;
      float mm = -1e30f, ss = 0.0f;
#pragma unroll 4
      for (int c = 0; c < CHUNKS; ++c) {
        const float cm = pshift[c];
        const float cs = ps[c * N + j];
        const float nm = fmaxf(mm, cm);
        ss = ss * __expf(mm - nm) + cs * __expf(cm - nm);
        mm = nm;
      }
      const float gv = __logf(bv[j]) - (mm + __logf(ss));
      G[j] = gv;
      const float bm = block_max(gv, sm4);
      if (tid == 0) gmaxp[bid] = bm;
    }
    gbar(bar, bid, ++bk);
  }

  // ---- cross-entropy: -(sum target * (10*M + F_i + G_j)) ----
  {
    float s = 0.0f;
    const float4* M4 = (const float4*)M;
    const float4* T4 = (const float4*)T;
    const float4* G4 = (const float4*)G;
    for (int v = bid * TPB + tid; v < NV4; v += NBLK * TPB) {
      const int row = v >> 11;
      const int gc = v & (N / 4 - 1);
      const float4 m4 = M4[v];
      const float4 t4 = T4[v];
      const float4 g4 = G4[gc];
      const float Fi = F[row];
      s += t4.x * (fmaf(m4.x, 10.0f, Fi) + g4.x);
      s += t4.y * (fmaf(m4.y, 10.0f, Fi) + g4.y);
      s += t4.z * (fmaf(m4.z, 10.0f, Fi) + g4.z);
      s += t4.w * (fmaf(m4.w, 10.0f, Fi) + g4.w);
    }
    s = block_sum(s, sm4);
    if (tid == 0) atomicAdd(acc, s);
  }
  gbar(bar, bid, ++bk);
  if (bid == 0 && tid == 0) out[0] = -acc[0];
}

extern "C" void kernel_launch(void* const* d_in, const int* in_sizes, int n_in,
                              void* d_out, int out_size, void* d_ws, size_t ws_size,
                              hipStream_t stream) {
  const float* M = (const float*)d_in[0];
  const float* T = (const float*)d_in[1];
  const float* av = (const float*)d_in[2];
  const float* bv = (const float*)d_in[3];
  float* out = (float*)d_out;

  float* ws = (float*)d_ws;
  float* F = ws;                       // N floats
  float* G = ws + N;                   // N floats
  float* ps = ws + 2 * N;              // CHUNKS*N floats (1 MB)
  float* pshift = ps + CHUNKS * N;     // CHUNKS floats
  float* gmaxp = pshift + CHUNKS;      // COL_TILES floats
  float* acc = gmaxp + COL_TILES;      // 1 float
  // barrier state, 128B-aligned
  size_t bar_off = (size_t)(2 * N + CHUNKS * N + CHUNKS + COL_TILES + 1);
  bar_off = (bar_off + 31) & ~(size_t)31;
  unsigned* bar = (unsigned*)(ws + bar_off);

  void* args[] = {&M, &T, &av, &bv, &out, &F, &G, &ps, &pshift, &gmaxp, &acc, &bar};
  hipLaunchCooperativeKernel((const void*)sinkhorn_kernel, dim3(NBLK), dim3(TPB),
                             args, 0, stream);
}